// Round 6
// baseline (114.258 us; speedup 1.0000x reference)
//
#include <hip/hip_runtime.h>

// Problem constants (from reference)
#define UPDATE_SIZE 4096
#define BATCH 256
#define NUM_UPDATES 8
#define NUM_CH 2
#define KEEP (NUM_UPDATES * UPDATE_SIZE)               // 32768
#define SNAP ((BATCH + NUM_UPDATES - 1) * UPDATE_SIZE) // 1077248
#define OUT_LEN (BATCH * UPDATE_SIZE)                  // 1048576 = 2^20

// float4-unit constants
#define OUT4 (OUT_LEN / 4)            // 262144 = 2^18
#define SNAP4 (SNAP / 4)              // 269312
#define REST4 ((SNAP - OUT_LEN) / 4)  // 7168
#define ROW4 (KEEP / 4)               // 8192 float4 per (b,c) update row
#define UPD4 (UPDATE_SIZE / 4)        // 1024
#define TOTAL4 (2 * OUT4 + 2 * SNAP4) // 1062912

// 2 elements per thread, phase-split (all 18 loads in flight before reduce)
#define KPT 2
#define NTHREADS (TOTAL4 / KPT)       // 531456 = 2076 * 256
// NTHREADS is a multiple of 1024 and all region boundaries are multiples of
// 1024 (in float4 units) -> q / region / validity are wave-uniform.

typedef float f32x4 __attribute__((ext_vector_type(4)));

__device__ __forceinline__ void decode(int idx, int& c, int& s4) {
  if (idx < 2 * OUT4) {
    c = idx >> 18;             // / OUT4
    s4 = idx & (OUT4 - 1);
  } else {
    const int r = idx - 2 * OUT4;
    c = (r >= SNAP4) ? 1 : 0;
    const int t4 = r - c * SNAP4;
    s4 = (t4 < REST4) ? (OUT4 + t4) : -1;   // -1 => zero-pad region
  }
}

// Issue all 9 loads for one element (PLAIN cached loads — R4 showed the
// nontemporal read path regresses). Data lands in u[0..8].
__device__ __forceinline__ void issue(int c, int s4,
                                      const f32x4* __restrict__ up4,
                                      const f32x4* __restrict__ sn4,
                                      f32x4* u) {
  const f32x4 z = {0.f, 0.f, 0.f, 0.f};
  if (s4 < 0) {
    #pragma unroll
    for (int k = 0; k < 9; ++k) u[k] = z;
    return;
  }
  u[8] = sn4[c * SNAP4 + s4];
  const int q = s4 >> 10;
  if (q >= 7 && q < BATCH) {
    // interior: exactly 8 covering windows; stride between consecutive b at
    // fixed s is NUM_CH*ROW4 - UPD4 = 15360 float4
    const int base0 = ((q - 7) * NUM_CH + c) * ROW4 + (s4 - (q - 7) * UPD4);
    #pragma unroll
    for (int k = 0; k < 8; ++k) {
      u[k] = up4[base0 + k * (NUM_CH * ROW4 - UPD4)];
    }
  } else {
    #pragma unroll
    for (int k = 0; k < 8; ++k) {
      const int b = q - 7 + k;
      const bool valid = (b >= 0) && (b < BATCH);
      u[k] = valid ? up4[(b * NUM_CH + c) * ROW4 + (s4 - b * UPD4)] : z;
    }
  }
}

__device__ __forceinline__ f32x4 reduce9(const f32x4* u) {
  // pairwise tree over the 8 update terms, then snapshot
  f32x4 s01 = u[0] + u[1], s23 = u[2] + u[3];
  f32x4 s45 = u[4] + u[5], s67 = u[6] + u[7];
  f32x4 s = (s01 + s23) + (s45 + s67);
  return u[8] + 0.125f * s;
}

__global__ __launch_bounds__(256) void OnlineAverager_62680752718461_kernel(
    const float* __restrict__ update,
    const float* __restrict__ snapshot,
    float* __restrict__ out) {
  const int tid = blockIdx.x * blockDim.x + threadIdx.x;

  const f32x4* __restrict__ up4 = reinterpret_cast<const f32x4*>(update);
  const f32x4* __restrict__ sn4 = reinterpret_cast<const f32x4*>(snapshot);
  f32x4* __restrict__ o4 = reinterpret_cast<f32x4*>(out);

  const int idx0 = tid;
  const int idx1 = tid + NTHREADS;

  int c0, s40, c1, s41;
  decode(idx0, c0, s40);
  decode(idx1, c1, s41);

  // Phase 1: issue all 18 loads back-to-back (no arithmetic between them),
  // so a wave has its full read set outstanding before the first vmcnt wait.
  f32x4 u0[9], u1[9];
  issue(c0, s40, up4, sn4, u0);
  issue(c1, s41, up4, sn4, u1);

  // Phase 2: reduce + stream-out (nt stores: stream-once output)
  const f32x4 acc0 = reduce9(u0);
  __builtin_nontemporal_store(acc0, &o4[idx0]);
  const f32x4 acc1 = reduce9(u1);
  __builtin_nontemporal_store(acc1, &o4[idx1]);
}

extern "C" void kernel_launch(void* const* d_in, const int* in_sizes, int n_in,
                              void* d_out, int out_size, void* d_ws, size_t ws_size,
                              hipStream_t stream) {
  const float* update = (const float*)d_in[0];   // (256, 2, 32768) f32
  const float* snapshot = (const float*)d_in[1]; // (2, 1077248) f32
  float* out = (float*)d_out;                    // (1,2,2^20) ++ (2,SNAP) f32

  const int threads = 256;
  const int blocks = NTHREADS / threads;         // 2076
  OnlineAverager_62680752718461_kernel<<<blocks, threads, 0, stream>>>(
      update, snapshot, out);
}

// Round 7
// 101.431 us; speedup vs baseline: 1.1265x; 1.1265x over previous
//
#include <hip/hip_runtime.h>

// Problem constants (from reference)
#define UPDATE_SIZE 4096
#define BATCH 256
#define NUM_UPDATES 8
#define NUM_CH 2
#define KEEP (NUM_UPDATES * UPDATE_SIZE)               // 32768
#define SNAP ((BATCH + NUM_UPDATES - 1) * UPDATE_SIZE) // 1077248
#define OUT_LEN (BATCH * UPDATE_SIZE)                  // 1048576 = 2^20

// float4-unit constants
#define OUT4 (OUT_LEN / 4)            // 262144 = 2^18
#define SNAP4 (SNAP / 4)              // 269312
#define REST4 ((SNAP - OUT_LEN) / 4)  // 7168
#define ROW4 (KEEP / 4)               // 8192 float4 per (b,c) update row
#define UPD4 (UPDATE_SIZE / 4)        // 1024
#define TOTAL4 (2 * OUT4 + 2 * SNAP4) // 1062912 = 4152 * 256

// 4 independent coalesced streams per thread (64 B stored / thread).
// Champion structure (R3): sequential per-element bodies, PLAIN cached loads
// (nt-load path regressed, R4), nontemporal stores (helped, R3), no explicit
// load batching (regressed, R4/R6 — compiler's own scheduler pipelines the
// unrolled bodies better than hand-batching, which blows VGPR live ranges).
#define KPT 4
#define NTHREADS (TOTAL4 / KPT)       // 265728 = 1038 * 256

typedef float f32x4 __attribute__((ext_vector_type(4)));

__device__ __forceinline__ f32x4 compute_elem(int idx,
                                              const f32x4* __restrict__ up4,
                                              const f32x4* __restrict__ sn4) {
  int c, s4;
  if (idx < 2 * OUT4) {
    c = idx >> 18;             // / OUT4
    s4 = idx & (OUT4 - 1);
  } else {
    const int r = idx - 2 * OUT4;
    c = (r >= SNAP4) ? 1 : 0;
    const int t4 = r - c * SNAP4;
    if (t4 >= REST4) {
      return (f32x4){0.f, 0.f, 0.f, 0.f};     // zero-pad of new_snapshot
    }
    s4 = OUT4 + t4;
  }

  const f32x4 sn = sn4[c * SNAP4 + s4];
  const int q = s4 >> 10;      // window index, uniform over the 4 packed floats
  if (q >= 7 && q < BATCH) {
    // interior: exactly 8 covering windows; pairwise tree shortens the
    // post-load dependency chain (strict FP won't reassociate a serial chain)
    const int base0 = ((q - 7) * NUM_CH + c) * ROW4 + (s4 - (q - 7) * UPD4);
    const int strd = NUM_CH * ROW4 - UPD4;   // stride between consecutive b
    const f32x4 s01 = up4[base0 + 0 * strd] + up4[base0 + 1 * strd];
    const f32x4 s23 = up4[base0 + 2 * strd] + up4[base0 + 3 * strd];
    const f32x4 s45 = up4[base0 + 4 * strd] + up4[base0 + 5 * strd];
    const f32x4 s67 = up4[base0 + 6 * strd] + up4[base0 + 7 * strd];
    return sn + 0.125f * ((s01 + s23) + (s45 + s67));
  } else {
    f32x4 acc = sn;
    const int blo = (q >= 7) ? (q - 7) : 0;
    const int bhi = (q < BATCH) ? q : (BATCH - 1);
    for (int b = blo; b <= bhi; ++b) {
      acc += 0.125f * up4[(b * NUM_CH + c) * ROW4 + (s4 - b * UPD4)];
    }
    return acc;
  }
}

__global__ __launch_bounds__(256) void OnlineAverager_62680752718461_kernel(
    const float* __restrict__ update,
    const float* __restrict__ snapshot,
    float* __restrict__ out) {
  const int tid = blockIdx.x * blockDim.x + threadIdx.x;

  const f32x4* __restrict__ up4 = reinterpret_cast<const f32x4*>(update);
  const f32x4* __restrict__ sn4 = reinterpret_cast<const f32x4*>(snapshot);
  f32x4* __restrict__ o4 = reinterpret_cast<f32x4*>(out);

  // 4 independent, fully-coalesced streams: idx = tid + k*NTHREADS.
  #pragma unroll
  for (int k = 0; k < KPT; ++k) {
    const int idx = tid + k * NTHREADS;
    const f32x4 acc = compute_elem(idx, up4, sn4);
    __builtin_nontemporal_store(acc, &o4[idx]);  // stream-once output
  }
}

extern "C" void kernel_launch(void* const* d_in, const int* in_sizes, int n_in,
                              void* d_out, int out_size, void* d_ws, size_t ws_size,
                              hipStream_t stream) {
  const float* update = (const float*)d_in[0];   // (256, 2, 32768) f32
  const float* snapshot = (const float*)d_in[1]; // (2, 1077248) f32
  float* out = (float*)d_out;                    // (1,2,2^20) ++ (2,SNAP) f32

  const int threads = 256;
  const int blocks = NTHREADS / threads;         // 1038
  OnlineAverager_62680752718461_kernel<<<blocks, threads, 0, stream>>>(
      update, snapshot, out);
}